// Round 10
// baseline (318.102 us; speedup 1.0000x reference)
//
#include <hip/hip_runtime.h>

// AttentionLayer: B=16, T=S=C=E=1024, NORM_C=0.5
// out  = (ctx @ w_out^T + b_out + x) * sqrt(.5)   [f32]
// attn = softmax(mask(h @ K))                     [f32]
// R10: fused GEMM2+mask+softmax (gemm_sm, 64xS strip per block, in-register
//      softmax, writes attn f32 + attn16 f16 in-place over h16); GEMM4
//      residual from x16 (EPI5). R9 gemm256 loop structure retained.

#define SCALE_F 0.70710678118654752440f

constexpr int BB = 16, TT = 1024, SS = 1024, CC = 1024, EE = 1024;

typedef float    f32x4 __attribute__((ext_vector_type(4)));
typedef _Float16 f16x8 __attribute__((ext_vector_type(8)));
typedef _Float16 f16x4 __attribute__((ext_vector_type(4)));

__device__ __forceinline__ void gload_lds16(const _Float16* g, _Float16* l) {
  __builtin_amdgcn_global_load_lds((const __attribute__((address_space(1))) void*)g,
                                   (__attribute__((address_space(3))) void*)l,
                                   16, 0, 0);
}
__device__ __forceinline__ void gload_lds4(const _Float16* g, _Float16* l) {
  __builtin_amdgcn_global_load_lds((const __attribute__((address_space(1))) void*)g,
                                   (__attribute__((address_space(3))) void*)l,
                                   4, 0, 0);
}

#define VMCNT(N) asm volatile("s_waitcnt vmcnt(" #N ")" ::: "memory")
#define LGKM(N)  asm volatile("s_waitcnt lgkmcnt(" #N ")" ::: "memory")
#define SBAR()   asm volatile("s_barrier" ::: "memory")
#define DSR(dst, a, off) \
  asm volatile("ds_read_b128 %0, %1 offset:" #off : "=v"(dst) : "v"(a))

// ---------------------------------------------------------------- conversions
__global__ __launch_bounds__(256) void cvt_f16(const float* __restrict__ s,
                                               _Float16* __restrict__ d, long n) {
  long i = ((long)blockIdx.x * 256 + threadIdx.x) * 8;
  if (i >= n) return;
  f32x4 a = *(const f32x4*)(s + i);
  f32x4 b = *(const f32x4*)(s + i + 4);
  f16x8 h;
  h[0]=(_Float16)a[0]; h[1]=(_Float16)a[1]; h[2]=(_Float16)a[2]; h[3]=(_Float16)a[3];
  h[4]=(_Float16)b[0]; h[5]=(_Float16)b[1]; h[6]=(_Float16)b[2]; h[7]=(_Float16)b[3];
  *(f16x8*)(d + i) = h;
}

// src: [B][R][Cc] f32  ->  dst: [B][Cc][R] f16
__global__ __launch_bounds__(256) void transpose_cvt(const float* __restrict__ src,
                                                     _Float16* __restrict__ dst,
                                                     int R, int Cc) {
  __shared__ float tile[64][65];
  const int b = blockIdx.z;
  const int r0 = blockIdx.y * 64, c0 = blockIdx.x * 64;
  const int t = threadIdx.x;
  const int tr = t >> 4, tc4 = (t & 15) * 4;
  const float* s = src + (size_t)b * R * Cc;
#pragma unroll
  for (int i = 0; i < 4; ++i) {
    f32x4 v = *(const f32x4*)(s + (size_t)(r0 + i * 16 + tr) * Cc + c0 + tc4);
    tile[i * 16 + tr][tc4 + 0] = v[0]; tile[i * 16 + tr][tc4 + 1] = v[1];
    tile[i * 16 + tr][tc4 + 2] = v[2]; tile[i * 16 + tr][tc4 + 3] = v[3];
  }
  __syncthreads();
  _Float16* d = dst + (size_t)b * Cc * R;
#pragma unroll
  for (int j = 0; j < 4; ++j) {
    const int cl = j * 16 + tr;
    f16x4 h;
    h[0] = (_Float16)tile[tc4 + 0][cl]; h[1] = (_Float16)tile[tc4 + 1][cl];
    h[2] = (_Float16)tile[tc4 + 2][cl]; h[3] = (_Float16)tile[tc4 + 3][cl];
    *(f16x4*)(d + (size_t)(c0 + cl) * R + r0 + tc4) = h;
  }
}

// ------------------------------------------------------------------- mask prep
__global__ __launch_bounds__(256) void mask_prep(const unsigned char* __restrict__ mraw,
                                                 float* __restrict__ maskneg,
                                                 float* __restrict__ sscale) {
  const int b = blockIdx.x, t = threadIdx.x;
  __shared__ int bytemode_sh, cnt_sh;
  if (t == 0) { bytemode_sh = 0; cnt_sh = 0; }
  __syncthreads();
  const unsigned int* mu = (const unsigned int*)mraw;
  int local = 0;
  for (int i = t; i < (BB * SS) / 4; i += 256) {
    unsigned int v = mu[i];
    if (v != 0u && v != 1u && v != 0x3f800000u) local = 1;
  }
  if (local) atomicOr(&bytemode_sh, 1);
  __syncthreads();
  const int bytemode = bytemode_sh;
  int cnt = 0;
  for (int s = t; s < SS; s += 256) {
    int m = bytemode ? (mraw[b * SS + s] != 0) : (mu[b * SS + s] != 0u);
    maskneg[b * SS + s] = m ? -__builtin_inff() : 0.0f;
    cnt += m;
  }
#pragma unroll
  for (int o = 32; o; o >>= 1) cnt += __shfl_down(cnt, o);
  if ((t & 63) == 0) atomicAdd(&cnt_sh, cnt);
  __syncthreads();
  if (t == 0) {
    float sv = (float)SS - (float)cnt_sh;
    sscale[b] = sv * rsqrtf(sv);
  }
}

// ---------------------------------------------------------------------- GEMM
// (R9 structure, verified) C[M,N] = A[M,K] @ Bmat[N,K]^T.
// EPI 1: h16=(acc+bias+addmat_f32)*S  EPI 3: ctx16=acc*extra[z]
// EPI 4: out=(acc+bias+addmat_f32)*S  EPI 5: out=(acc+bias+addmat_f16)*S
template <int EPI>
__global__ __launch_bounds__(512, 2)
void gemm256(const _Float16* __restrict__ A, const _Float16* __restrict__ Bmat,
             long aStride, long bStride, long oStride,
             int M, int N, int K,
             void* __restrict__ outp,
             const float* __restrict__ bias,
             const void* __restrict__ addmat,
             const float* __restrict__ extra) {
  __shared__ __attribute__((aligned(16))) _Float16 smem[65536];  // 128 KB

  const int t = threadIdx.x;
  const int lane = t & 63;
  const int wid = t >> 6;
  const int wm = wid >> 2, wn = wid & 3;
  const int z = blockIdx.z;
  const int lo = lane & 15, hi = lane >> 4;
  const int sx = lo & 7;
  const int nt = K >> 6;                     // 16

  const int gx = gridDim.x;
  const int fblk = blockIdx.x + blockIdx.y * gx;
  const int q = (gx * gridDim.y) >> 3;
  const int wg = (fblk & 7) * q + (fblk >> 3);
  const long rowBase = (long)(wg / gx) * 256;
  const long colBase = (long)(wg % gx) * 256;

  const _Float16* Ag = A + (size_t)z * aStride + rowBase * K;
  const _Float16* Bg = Bmat + (size_t)z * bStride + colBase * K;

  const int sr8 = t >> 3;
  const int srck = (((t & 7) ^ (sr8 & 7)) << 3);

  f32x4 acc[8][4] = {};

#define STAGE8(U)                                                              \
  {                                                                            \
    const int tu_ = (U);                                                       \
    _Float16* db_ = &smem[(tu_ & 1) * 32768];                                  \
    const size_t kb_ = (size_t)tu_ * 64 + srck;                                \
    _Pragma("unroll") for (int i_ = 0; i_ < 4; ++i_)                           \
      gload_lds16(Ag + (size_t)(i_ * 64 + sr8) * K + kb_,                      \
                  db_ + i_ * 4096 + t * 8);                                    \
    _Pragma("unroll") for (int i_ = 0; i_ < 4; ++i_)                           \
      gload_lds16(Bg + (size_t)(i_ * 64 + sr8) * K + kb_,                      \
                  db_ + 16384 + i_ * 4096 + t * 8);                            \
  }

  const int lds0 = (int)(size_t)&smem[0];
  const int abase = lds0 + (wm * 128 + lo) * 128 + ((hi ^ sx) << 4);
  const int bbase = lds0 + 32768 + (wn * 64 + lo) * 128 + ((hi ^ sx) << 4);

  STAGE8(0)
  STAGE8(1)
  VMCNT(8);
  SBAR();

  for (int u = 0; u < nt; ++u) {
    const int bo = (u & 1) << 16;
    const int aad = abase + bo, bad = bbase + bo;
    const int aad1 = aad ^ 64, bad1 = bad ^ 64;
    f16x8 a0[8], b0[4], a1[8], b1[4];
    DSR(a0[0], aad, 0);     DSR(a0[1], aad, 2048);  DSR(a0[2], aad, 4096);
    DSR(a0[3], aad, 6144);  DSR(a0[4], aad, 8192);  DSR(a0[5], aad, 10240);
    DSR(a0[6], aad, 12288); DSR(a0[7], aad, 14336);
    DSR(b0[0], bad, 0);     DSR(b0[1], bad, 2048);  DSR(b0[2], bad, 4096);
    DSR(b0[3], bad, 6144);
    DSR(a1[0], aad1, 0);     DSR(a1[1], aad1, 2048);  DSR(a1[2], aad1, 4096);
    DSR(a1[3], aad1, 6144);  DSR(a1[4], aad1, 8192);  DSR(a1[5], aad1, 10240);
    DSR(a1[6], aad1, 12288); DSR(a1[7], aad1, 14336);
    DSR(b1[0], bad1, 0);     DSR(b1[1], bad1, 2048);  DSR(b1[2], bad1, 4096);
    DSR(b1[3], bad1, 6144);
    LGKM(12);
    __builtin_amdgcn_sched_barrier(0);
    __builtin_amdgcn_s_setprio(1);
#pragma unroll
    for (int mi = 0; mi < 8; ++mi)
#pragma unroll
      for (int ni = 0; ni < 4; ++ni)
        acc[mi][ni] = __builtin_amdgcn_mfma_f32_16x16x32_f16(a0[mi], b0[ni],
                                                             acc[mi][ni], 0, 0, 0);
    __builtin_amdgcn_s_setprio(0);
    LGKM(0);
    __builtin_amdgcn_sched_barrier(0);
    SBAR();
    if (u + 2 < nt) STAGE8(u + 2)
    __builtin_amdgcn_s_setprio(1);
#pragma unroll
    for (int mi = 0; mi < 8; ++mi)
#pragma unroll
      for (int ni = 0; ni < 4; ++ni)
        acc[mi][ni] = __builtin_amdgcn_mfma_f32_16x16x32_f16(a1[mi], b1[ni],
                                                             acc[mi][ni], 0, 0, 0);
    __builtin_amdgcn_s_setprio(0);
    if (u + 2 < nt)       { VMCNT(8); }
    else if (u + 2 == nt) { VMCNT(0); }
    SBAR();
  }

  // ---- vectorized epilogue
  constexpr int EPS = 68;
  const int fr = lane & 15;
  const int fq = (lane >> 4) * 4;
  const int er = lane >> 2;
  const int ec = (lane & 3) * 16;
  const long gc0 = colBase + wn * 64 + ec;
  float* ep = (float*)smem + wid * (16 * EPS);

  f32x4 biasv[4], av[4];
  float sc = 0.f;
  auto load_add = [&](long gr) {
    if constexpr (EPI == 1 || EPI == 4) {
      const float* am = (const float*)addmat;
#pragma unroll
      for (int i = 0; i < 4; ++i) av[i] = *(const f32x4*)&am[gr * N + gc0 + i * 4];
    } else if constexpr (EPI == 5) {
      const _Float16* am = (const _Float16*)addmat;
      f16x8 h0 = *(const f16x8*)&am[gr * N + gc0];
      f16x8 h1 = *(const f16x8*)&am[gr * N + gc0 + 8];
#pragma unroll
      for (int i = 0; i < 4; ++i) {
        const f16x8& hh = i < 2 ? h0 : h1;
        const int o = (i & 1) * 4;
        av[i][0] = (float)hh[o]; av[i][1] = (float)hh[o + 1];
        av[i][2] = (float)hh[o + 2]; av[i][3] = (float)hh[o + 3];
      }
    }
  };
  if constexpr (EPI == 1 || EPI == 4 || EPI == 5) {
#pragma unroll
    for (int i = 0; i < 4; ++i) biasv[i] = *(const f32x4*)&bias[gc0 + i * 4];
    load_add(rowBase + wm * 128 + er);
  }
  if constexpr (EPI == 3) sc = extra[z];

  __syncthreads();
#pragma unroll
  for (int mf = 0; mf < 8; ++mf) {
#pragma unroll
    for (int n = 0; n < 4; ++n)
#pragma unroll
      for (int j = 0; j < 4; ++j)
        ep[(fq + j) * EPS + n * 16 + fr] = acc[mf][n][j];
    __syncthreads();
    const long gr = rowBase + wm * 128 + mf * 16 + er;
    f32x4 r[4];
#pragma unroll
    for (int i = 0; i < 4; ++i) r[i] = *(const f32x4*)&ep[er * EPS + ec + i * 4];
    f32x4 a_cur[4];
    if constexpr (EPI == 1 || EPI == 4 || EPI == 5) {
#pragma unroll
      for (int i = 0; i < 4; ++i) a_cur[i] = av[i];
      if (mf < 7) load_add(gr + 16);
    }
    if constexpr (EPI == 1) {
      _Float16* o = (_Float16*)outp + gr * N + gc0;
#pragma unroll
      for (int g = 0; g < 2; ++g) {
        f32x4 v0 = (r[2 * g] + biasv[2 * g] + a_cur[2 * g]) * SCALE_F;
        f32x4 v1 = (r[2 * g + 1] + biasv[2 * g + 1] + a_cur[2 * g + 1]) * SCALE_F;
        f16x8 h;
        h[0]=(_Float16)v0[0]; h[1]=(_Float16)v0[1]; h[2]=(_Float16)v0[2]; h[3]=(_Float16)v0[3];
        h[4]=(_Float16)v1[0]; h[5]=(_Float16)v1[1]; h[6]=(_Float16)v1[2]; h[7]=(_Float16)v1[3];
        *(f16x8*)(o + g * 8) = h;
      }
    } else if constexpr (EPI == 3) {
      _Float16* o = (_Float16*)outp + (size_t)z * oStride + gr * N + gc0;
#pragma unroll
      for (int g = 0; g < 2; ++g) {
        f32x4 v0 = r[2 * g] * sc;
        f32x4 v1 = r[2 * g + 1] * sc;
        f16x8 h;
        h[0]=(_Float16)v0[0]; h[1]=(_Float16)v0[1]; h[2]=(_Float16)v0[2]; h[3]=(_Float16)v0[3];
        h[4]=(_Float16)v1[0]; h[5]=(_Float16)v1[1]; h[6]=(_Float16)v1[2]; h[7]=(_Float16)v1[3];
        *(f16x8*)(o + g * 8) = h;
      }
    } else {
      float* o = (float*)outp + gr * N + gc0;
#pragma unroll
      for (int i = 0; i < 4; ++i)
        *(f32x4*)(o + i * 4) = (r[i] + biasv[i] + a_cur[i]) * SCALE_F;
    }
    __syncthreads();
  }
}

// --------------------------------------------- fused GEMM2 + mask + softmax
// Block = 64 rows x full S=1024 of one batch. 512 thr (8 waves); wave covers
// all 64 rows x 128 cols (acc[4][8]). BK=32 (one MFMA k-step/tile), 32 tiles.
// LDS: B dbuf 2x64KB [1024 n][32 k] + A dbuf 2x4KB [64 r][32 k] = 136 KB.
// Swizzle (64B rows, 4x16B slots): slot s of row r holds k-chunk s^(r&3).
// Sync = R9 ledger: uniform 10 VMEM loads/thread/tile, dist-2 prefetch,
// VMCNT(10)+SBAR at tile end, mid-tile SBAR before overwrite-staging.
// Epilogue: +maskneg, row-max (shfl_xor in 16-lane col group + 2-stage LDS),
// exp, row-sum, scale; write attn f32 (d_out) and attn16 (in-place over h16:
// each block touches only its own 64 rows - no cross-block hazard).
__global__ __launch_bounds__(512, 2)
void gemm_sm(const _Float16* __restrict__ h16, const _Float16* __restrict__ keysT,
             const float* __restrict__ maskneg,
             float* __restrict__ attn, _Float16* __restrict__ attn16) {
  __shared__ __attribute__((aligned(16))) _Float16 smem[69632];  // 136 KB

  const int t = threadIdx.x;
  const int lane = t & 63;
  const int wid = t >> 6;
  const int lo = lane & 15, hi = lane >> 4;

  // XCD swizzle (256 blocks, q=32): XCD k serves 32 consecutive logical wgs
  const int wg = ((int)blockIdx.x & 7) * 32 + ((int)blockIdx.x >> 3);
  const int z = wg >> 4;
  const long rowBase = (long)(wg & 15) * 64;

  const _Float16* Ag = h16 + ((size_t)z * TT + rowBase) * EE;
  const _Float16* Bg = keysT + (size_t)z * SS * EE;

  // staging constants (wave-uniform dest bases; inverse-swizzled source)
  const int bn_lo = t >> 2;                      // n within 128-group
  const int bslot = t & 3;
  const int bchunk = bslot ^ (bn_lo & 3);        // n&3 == bn_lo&3
  const int arow0 = t >> 4;                      // A row, load 0 (load1: +32)
  const int aslot = (t >> 2) & 3;
  const int achunk = aslot ^ (arow0 & 3);        // row&3 same both loads
  const int adw = t & 3;

  f32x4 acc[4][8] = {};

#define STG(U)                                                                 \
  {                                                                            \
    _Float16* Bb_ = &smem[((U) & 1) * 32768];                                  \
    _Float16* Ab_ = &smem[65536 + ((U) & 1) * 2048];                           \
    const size_t ku_ = (size_t)(U) * 32;                                       \
    _Pragma("unroll") for (int i_ = 0; i_ < 8; ++i_) {                         \
      const int n_ = i_ * 128 + bn_lo;                                         \
      gload_lds16(Bg + (size_t)n_ * EE + ku_ + (bchunk << 3),                  \
                  Bb_ + n_ * 32 + bslot * 8);                                  \
    }                                                                          \
    _Pragma("unroll") for (int i_ = 0; i_ < 2; ++i_) {                         \
      const int r_ = i_ * 32 + arow0;                                          \
      gload_lds4(Ag + (size_t)r_ * EE + ku_ + achunk * 8 + adw * 2,            \
                 Ab_ + (i_ * 512 + t) * 2);                                    \
    }                                                                          \
  }

  const int lds0 = (int)(size_t)&smem[0];
  const int abase = lds0 + 131072 + lo * 64 + ((hi ^ (lo & 3)) << 4);
  const int bbase = lds0 + wid * 8192 + lo * 64 + ((hi ^ (lo & 3)) << 4);

  STG(0)
  STG(1)
  VMCNT(10);
  SBAR();

  for (int u = 0; u < 32; ++u) {
    const int aad = abase + ((u & 1) << 12);
    const int bad = bbase + ((u & 1) << 16);
    f16x8 a[4], b[8];
    DSR(a[0], aad, 0);    DSR(a[1], aad, 1024); DSR(a[2], aad, 2048);
    DSR(a[3], aad, 3072);
    DSR(b[0], bad, 0);    DSR(b[1], bad, 1024); DSR(b[2], bad, 2048);
    DSR(b[3], bad, 3072); DSR(b[4], bad, 4096); DSR(b[5], bad, 5120);
    DSR(b[6], bad, 6144); DSR(b[7], bad, 7168);
    LGKM(6);                                     // a[0..3], b[0..1] ready
    __builtin_amdgcn_sched_barrier(0);
    __builtin_amdgcn_s_setprio(1);
#pragma unroll
    for (int ni = 0; ni < 2; ++ni)
#pragma unroll
      for (int mi = 0; mi < 4; ++mi)
        acc[mi][ni] = __builtin_amdgcn_mfma_f32_16x16x32_f16(a[mi], b[ni],
                                                             acc[mi][ni], 0, 0, 0);
    __builtin_amdgcn_s_setprio(0);
    LGKM(0);
    __builtin_amdgcn_sched_barrier(0);
    SBAR();                                      // all waves done reading buf
    if (u + 2 < 32) STG(u + 2)                   // overwrite-safe
    __builtin_amdgcn_s_setprio(1);
#pragma unroll
    for (int ni = 2; ni < 8; ++ni)
#pragma unroll
      for (int mi = 0; mi < 4; ++mi)
        acc[mi][ni] = __builtin_amdgcn_mfma_f32_16x16x32_f16(a[mi], b[ni],
                                                             acc[mi][ni], 0, 0, 0);
    __builtin_amdgcn_s_setprio(0);
    if (u + 2 < 32)       { VMCNT(10); }
    else if (u + 2 == 32) { VMCNT(0); }
    SBAR();
  }

  // ---------------- fused mask + softmax (rows are block-local 0..63)
  float* redm   = (float*)smem;          // [8][64]
  float* redf   = (float*)smem + 512;    // [64] final max
  float* redsum = (float*)smem + 576;    // [8][64]
  float* redl   = (float*)smem + 1088;   // [64] 1/sum
  float* epb    = (float*)smem + 2048;   // per-wave 16x132 transpose regions

  float mk[8];
#pragma unroll
  for (int ni = 0; ni < 8; ++ni)
    mk[ni] = maskneg[z * SS + wid * 128 + ni * 16 + lo];

  // row-max
  float rmax[4][4];
#pragma unroll
  for (int mi = 0; mi < 4; ++mi)
#pragma unroll
    for (int j = 0; j < 4; ++j) {
      float v = -__builtin_inff();
#pragma unroll
      for (int ni = 0; ni < 8; ++ni) {
        acc[mi][ni][j] += mk[ni];
        v = fmaxf(v, acc[mi][ni][j]);
      }
#pragma unroll
      for (int o = 1; o < 16; o <<= 1) v = fmaxf(v, __shfl_xor(v, o));
      rmax[mi][j] = v;
    }
  if (lo == 0) {
#pragma unroll
    for (int mi = 0; mi < 4; ++mi)
#pragma unroll
      for (int j = 0; j < 4; ++j)
        redm[wid * 64 + mi * 16 + hi * 4 + j] = rmax[mi][j];
  }
  __syncthreads();
  if (t < 64) {
    float m = redm[t];
#pragma unroll
    for (int w = 1; w < 8; ++w) m = fmaxf(m, redm[w * 64 + t]);
    redf[t] = m;
  }
  __syncthreads();
  // exp + row-sum
#pragma unroll
  for (int mi = 0; mi < 4; ++mi)
#pragma unroll
    for (int j = 0; j < 4; ++j) {
      const float m = redf[mi * 16 + hi * 4 + j];
      float s = 0.f;
#pragma unroll
      for (int ni = 0; ni < 8; ++ni) {
        float e = __expf(acc[mi][ni][j] - m);
        acc[mi][ni][j] = e;
        s += e;
      }
#pragma unroll
      for (int o = 1; o < 16; o <<= 1) s += __shfl_xor(s, o);
      rmax[mi][j] = s;
    }
  if (lo == 0) {
#pragma unroll
    for (int mi = 0; mi < 4; ++mi)
#pragma unroll
      for (int j = 0; j < 4; ++j)
        redsum[wid * 64 + mi * 16 + hi * 4 + j] = rmax[mi][j];
  }
  __syncthreads();
  if (t < 64) {
    float s = redsum[t];
#pragma unroll
    for (int w = 1; w < 8; ++w) s += redsum[w * 64 + t];
    redl[t] = 1.0f / s;
  }
  __syncthreads();
#pragma unroll
  for (int mi = 0; mi < 4; ++mi)
#pragma unroll
    for (int j = 0; j < 4; ++j) {
      const float inv = redl[mi * 16 + hi * 4 + j];
#pragma unroll
      for (int ni = 0; ni < 8; ++ni) acc[mi][ni][j] *= inv;
    }

  // ---------------- coalesced writes via per-wave LDS transpose
  float* ep = epb + wid * (16 * 132);
  const int rr = lane >> 2;
  const int cc = (lane & 3) * 32;
#pragma unroll
  for (int mi = 0; mi < 4; ++mi) {
#pragma unroll
    for (int ni = 0; ni < 8; ++ni)
#pragma unroll
      for (int j = 0; j < 4; ++j)
        ep[(hi * 4 + j) * 132 + ni * 16 + lo] = acc[mi][ni][j];
    __syncthreads();
    f32x4 r4[8];
#pragma unroll
    for (int i = 0; i < 8; ++i) r4[i] = *(const f32x4*)&ep[rr * 132 + cc + i * 4];
    const size_t base = ((size_t)z << 20) + ((size_t)(rowBase + mi * 16 + rr) << 10)
                        + wid * 128 + cc;
    float* ao = attn + base;
#pragma unroll
    for (int i = 0; i < 8; ++i) *(f32x4*)(ao + i * 4) = r4[i];
    _Float16* ho = attn16 + base;
#pragma unroll
    for (int g = 0; g < 4; ++g) {
      f16x8 h;
      h[0]=(_Float16)r4[2*g][0]; h[1]=(_Float16)r4[2*g][1];
      h[2]=(_Float16)r4[2*g][2]; h[3]=(_Float16)r4[2*g][3];
      h[4]=(_Float16)r4[2*g+1][0]; h[5]=(_Float16)r4[2*g+1][1];
      h[6]=(_Float16)r4[2*g+1][2]; h[7]=(_Float16)r4[2*g+1][3];
      *(f16x8*)(ho + g * 8) = h;
    }
    __syncthreads();
  }
}

// -------------------------------------------------------------------- launch
extern "C" void kernel_launch(void* const* d_in, const int* in_sizes, int n_in,
                              void* d_out, int out_size, void* d_ws, size_t ws_size,
                              hipStream_t stream) {
  const float* x     = (const float*)d_in[0];
  const float* te    = (const float*)d_in[1];
  const float* keys  = (const float*)d_in[2];
  const float* vals  = (const float*)d_in[3];
  const void*  mask  = d_in[4];
  const float* w_in  = (const float*)d_in[5];
  const float* b_in  = (const float*)d_in[6];
  const float* w_out = (const float*)d_in[7];
  const float* b_out = (const float*)d_in[8];

  char* ws = (char*)d_ws;
  const size_t MB32 = 33554432;
  _Float16* buf0   = (_Float16*)(ws);              // x16 (lives to the end)
  _Float16* buf1   = (_Float16*)(ws + MB32);       // h16 -> attn16 (in place)
  _Float16* keysT  = (_Float16*)(ws + 2 * MB32);   // keysT -> ctx16 after sm
  _Float16* valsT  = (_Float16*)(ws + 3 * MB32);
  _Float16* win16  = (_Float16*)(ws + 4 * MB32);
  _Float16* wout16 = (_Float16*)(ws + 4 * MB32 + 2097152);
  float*    maskneg= (float*)   (ws + 4 * MB32 + 2 * 2097152);
  float*    sscale = (float*)   (ws + 4 * MB32 + 2 * 2097152 + 65536);

  float* out_main = (float*)d_out;
  float* attn_out = (float*)d_out + (size_t)BB * TT * CC;

  cvt_f16<<<dim3(16777216 / 2048), 256, 0, stream>>>(x, buf0, 16777216);
  cvt_f16<<<dim3(1048576 / 2048), 256, 0, stream>>>(w_in, win16, 1048576);
  cvt_f16<<<dim3(1048576 / 2048), 256, 0, stream>>>(w_out, wout16, 1048576);
  transpose_cvt<<<dim3(SS / 64, EE / 64, BB), 256, 0, stream>>>(keys, keysT, EE, SS);
  transpose_cvt<<<dim3(EE / 64, SS / 64, BB), 256, 0, stream>>>(vals, valsT, SS, EE);
  mask_prep<<<dim3(BB), 256, 0, stream>>>((const unsigned char*)mask, maskneg, sscale);

  // GEMM1: h16 = (x16 @ w_in^T + b_in + te)*s
  gemm256<1><<<dim3(EE / 256, (BB * TT) / 256, 1), 512, 0, stream>>>(
      buf0, win16, 0, 0, 0, BB * TT, EE, CC, buf1, b_in, te, nullptr);
  // fused GEMM2 + mask + softmax -> attn f32 (d_out) + attn16 (in-place buf1)
  gemm_sm<<<dim3(256), 512, 0, stream>>>(buf1, keysT, maskneg, attn_out, buf1);
  // GEMM3: ctx16 = (attn16 @ valsT^T)*sqrt(s_b)  -> keysT region (x16 survives)
  gemm256<3><<<dim3(EE / 256, TT / 256, BB), 512, 0, stream>>>(
      buf1, valsT, (long)TT * SS, (long)EE * SS, (long)TT * EE,
      TT, EE, SS, keysT, nullptr, nullptr, sscale);
  // GEMM4: out = (ctx16 @ w_out^T + b_out + x16)*s   (f16 residual, EPI5)
  gemm256<5><<<dim3(CC / 256, (BB * TT) / 256, 1), 512, 0, stream>>>(
      keysT, wout16, 0, 0, 0, BB * TT, CC, EE, out_main, b_out, buf0, nullptr);
}

// Round 11
// 314.299 us; speedup vs baseline: 1.0121x; 1.0121x over previous
//
#include <hip/hip_runtime.h>

// AttentionLayer: B=16, T=S=C=E=1024, NORM_C=0.5
// out  = (ctx @ w_out^T + b_out + x) * sqrt(.5)   [f32]
// attn = softmax(mask(h @ K))                     [f32]
// R11: m201-faithful 8-phase GEMM on the R9 geometry. Per phase: 8 asm
//      ds_read (one (mh,ks) quadrant) + 2-load region stage + SBAR+lgkm0 +
//      16 MFMA (setprio) + vmcnt(4)+SBAR. LDS [op][buf][khalf][256][64B],
//      slot = chunk ^ ((row>>1)&3). No fusion (gemm_sm reverted); EPI5 kept.

#define SCALE_F 0.70710678118654752440f

constexpr int BB = 16, TT = 1024, SS = 1024, CC = 1024, EE = 1024;

typedef float    f32x4 __attribute__((ext_vector_type(4)));
typedef _Float16 f16x8 __attribute__((ext_vector_type(8)));
typedef _Float16 f16x4 __attribute__((ext_vector_type(4)));

__device__ __forceinline__ void gload_lds16(const _Float16* g, _Float16* l) {
  __builtin_amdgcn_global_load_lds((const __attribute__((address_space(1))) void*)g,
                                   (__attribute__((address_space(3))) void*)l,
                                   16, 0, 0);
}

#define VMCNT(N) asm volatile("s_waitcnt vmcnt(" #N ")" ::: "memory")
#define LGKM(N)  asm volatile("s_waitcnt lgkmcnt(" #N ")" ::: "memory")
#define SBAR()   asm volatile("s_barrier" ::: "memory")
#define DSR(dst, a, off) \
  asm volatile("ds_read_b128 %0, %1 offset:" #off : "=v"(dst) : "v"(a))

// ---------------------------------------------------------------- conversions
__global__ __launch_bounds__(256) void cvt_f16(const float* __restrict__ s,
                                               _Float16* __restrict__ d, long n) {
  long i = ((long)blockIdx.x * 256 + threadIdx.x) * 8;
  if (i >= n) return;
  f32x4 a = *(const f32x4*)(s + i);
  f32x4 b = *(const f32x4*)(s + i + 4);
  f16x8 h;
  h[0]=(_Float16)a[0]; h[1]=(_Float16)a[1]; h[2]=(_Float16)a[2]; h[3]=(_Float16)a[3];
  h[4]=(_Float16)b[0]; h[5]=(_Float16)b[1]; h[6]=(_Float16)b[2]; h[7]=(_Float16)b[3];
  *(f16x8*)(d + i) = h;
}

// src: [B][R][Cc] f32  ->  dst: [B][Cc][R] f16
__global__ __launch_bounds__(256) void transpose_cvt(const float* __restrict__ src,
                                                     _Float16* __restrict__ dst,
                                                     int R, int Cc) {
  __shared__ float tile[64][65];
  const int b = blockIdx.z;
  const int r0 = blockIdx.y * 64, c0 = blockIdx.x * 64;
  const int t = threadIdx.x;
  const int tr = t >> 4, tc4 = (t & 15) * 4;
  const float* s = src + (size_t)b * R * Cc;
#pragma unroll
  for (int i = 0; i < 4; ++i) {
    f32x4 v = *(const f32x4*)(s + (size_t)(r0 + i * 16 + tr) * Cc + c0 + tc4);
    tile[i * 16 + tr][tc4 + 0] = v[0]; tile[i * 16 + tr][tc4 + 1] = v[1];
    tile[i * 16 + tr][tc4 + 2] = v[2]; tile[i * 16 + tr][tc4 + 3] = v[3];
  }
  __syncthreads();
  _Float16* d = dst + (size_t)b * Cc * R;
#pragma unroll
  for (int j = 0; j < 4; ++j) {
    const int cl = j * 16 + tr;
    f16x4 h;
    h[0] = (_Float16)tile[tc4 + 0][cl]; h[1] = (_Float16)tile[tc4 + 1][cl];
    h[2] = (_Float16)tile[tc4 + 2][cl]; h[3] = (_Float16)tile[tc4 + 3][cl];
    *(f16x4*)(d + (size_t)(c0 + cl) * R + r0 + tc4) = h;
  }
}

// ------------------------------------------------------------------- mask prep
__global__ __launch_bounds__(256) void mask_prep(const unsigned char* __restrict__ mraw,
                                                 float* __restrict__ maskneg,
                                                 float* __restrict__ sscale) {
  const int b = blockIdx.x, t = threadIdx.x;
  __shared__ int bytemode_sh, cnt_sh;
  if (t == 0) { bytemode_sh = 0; cnt_sh = 0; }
  __syncthreads();
  const unsigned int* mu = (const unsigned int*)mraw;
  int local = 0;
  for (int i = t; i < (BB * SS) / 4; i += 256) {
    unsigned int v = mu[i];
    if (v != 0u && v != 1u && v != 0x3f800000u) local = 1;
  }
  if (local) atomicOr(&bytemode_sh, 1);
  __syncthreads();
  const int bytemode = bytemode_sh;
  int cnt = 0;
  for (int s = t; s < SS; s += 256) {
    int m = bytemode ? (mraw[b * SS + s] != 0) : (mu[b * SS + s] != 0u);
    maskneg[b * SS + s] = m ? -__builtin_inff() : 0.0f;
    cnt += m;
  }
#pragma unroll
  for (int o = 32; o; o >>= 1) cnt += __shfl_down(cnt, o);
  if ((t & 63) == 0) atomicAdd(&cnt_sh, cnt);
  __syncthreads();
  if (t == 0) {
    float sv = (float)SS - (float)cnt_sh;
    sscale[b] = sv * rsqrtf(sv);
  }
}

// ---------------------------------------------------------------------- GEMM
// C[M,N] = A[M,K] @ Bmat[N,K]^T ; fp16 K-major, f32 accum.
// BM=BN=256, BK=64; 512 thr = 8 waves (wm 0..1 x wn 0..3); wave tile 128x64,
// acc[8][4] (acc[MH*4+mi][ni], C-row = wm*128+MH*64+mi*16+fq+j).
// LDS 128KB bytes: A: buf*32768 + kh*16384 + r*64 + slot*16 ; B: +65536.
// slot s of row r holds k-chunk s ^ ((r>>1)&3)  (2-way bank aliasing = free).
// 8 phases per 2 tiles; phase = {8 ds_read quadrant | 2-load region stage |
// SBAR | lgkm0+schedbar | setprio 16 MFMA | vmcnt(4) | SBAR}.
// Stage plan (phase g, global): region (T=(g+4)>>2, q=(g+4)&3), q: 0=A-kh0,
// 1=B-kh0, 2=A-kh1, 3=B-kh1 -> every region lands 3-5 phases before first
// read and 1+ phase after previous occupant's last read (no races);
// vmcnt(4) with 2 loads/phase guarantees everything >2 phases old landed.
// EPI 1: h16=(acc+bias+add_f32)*S  EPI 2: scores=acc+maskneg
// EPI 3: ctx16=acc*extra[z]        EPI 5: out=(acc+bias+add_f16)*S
template <int EPI>
__global__ __launch_bounds__(512, 2)
void gemm8p(const _Float16* __restrict__ A, const _Float16* __restrict__ Bmat,
            long aStride, long bStride, long oStride,
            int M, int N, int K,
            void* __restrict__ outp,
            const float* __restrict__ bias,
            const void* __restrict__ addmat,
            const float* __restrict__ extra) {
  __shared__ __attribute__((aligned(16))) _Float16 smem[65536];  // 128 KB

  const int t = threadIdx.x;
  const int lane = t & 63;
  const int wid = t >> 6;
  const int wm = wid >> 2, wn = wid & 3;
  const int z = blockIdx.z;
  const int lo = lane & 15, hi = lane >> 4;
  const int nt = K >> 6;                     // 16 (even, >=4)

  // XCD-aware bijective swizzle (gx*gy % 8 == 0 for all our grids)
  const int gx = gridDim.x;
  const int fblk = blockIdx.x + blockIdx.y * gx;
  const int q = (gx * gridDim.y) >> 3;
  const int wg = (fblk & 7) * q + (fblk >> 3);
  const long rowBase = (long)(wg / gx) * 256;
  const long colBase = (long)(wg % gx) * 256;

  const _Float16* Ag = A + (size_t)z * aStride + rowBase * K;
  const _Float16* Bg = Bmat + (size_t)z * bStride + colBase * K;

  // staging: lane l -> row 128*i + (l>>2), slot l&3 (dest linear);
  // source chunk = (l&3) ^ ((l>>3)&3)  (inverse of the read-side swizzle)
  const int strow = t >> 2;                       // row within 128-group
  const int stchunk = (t & 3) ^ ((t >> 3) & 3);   // k-chunk (8 f16) to fetch

  f32x4 acc[8][4] = {};

  // stage region (T,Q): Q: 0=A-kh0 1=B-kh0 2=A-kh1 3=B-kh1 (2 loads)
#define STG(T, Q)                                                              \
  if ((T) < nt) {                                                              \
    const int op_ = (Q) & 1, kh_ = (Q) >> 1;                                   \
    const _Float16* g_ = op_ ? Bg : Ag;                                        \
    _Float16* db_ = &smem[op_ * 32768 + ((T) & 1) * 16384 + kh_ * 8192];       \
    const size_t ko_ = (size_t)(T) * 64 + kh_ * 32 + stchunk * 8;              \
    gload_lds16(g_ + (size_t)strow * K + ko_, db_ + t * 8);                    \
    gload_lds16(g_ + (size_t)(128 + strow) * K + ko_, db_ + 4096 + t * 8);     \
  }

  // fragment read bases (bytes); phase adds buf/ks/mh offsets
  const int lds0 = (int)(size_t)&smem[0];
  const int slotx = (hi ^ ((lo >> 1) & 3)) << 4;
  const int abase = lds0 + wm * 8192 + lo * 64 + slotx;
  const int bbase = lds0 + 65536 + wn * 4096 + lo * 64 + slotx;

#define PH(MH, KS, U, TS, QQ)                                                  \
  {                                                                            \
    const int aad = abase + ((U) & 1) * 32768 + (KS) * 16384 + (MH) * 4096;    \
    const int bad = bbase + ((U) & 1) * 32768 + (KS) * 16384;                  \
    f16x8 a_[4], b_[4];                                                        \
    DSR(a_[0], aad, 0); DSR(a_[1], aad, 1024);                                 \
    DSR(a_[2], aad, 2048); DSR(a_[3], aad, 3072);                              \
    DSR(b_[0], bad, 0); DSR(b_[1], bad, 1024);                                 \
    DSR(b_[2], bad, 2048); DSR(b_[3], bad, 3072);                              \
    STG(TS, QQ)                                                                \
    SBAR();                                                                    \
    LGKM(0);                                                                   \
    __builtin_amdgcn_sched_barrier(0);                                         \
    __builtin_amdgcn_s_setprio(1);                                             \
    _Pragma("unroll") for (int mi_ = 0; mi_ < 4; ++mi_)                        \
      _Pragma("unroll") for (int ni_ = 0; ni_ < 4; ++ni_)                      \
        acc[(MH) * 4 + mi_][ni_] = __builtin_amdgcn_mfma_f32_16x16x32_f16(     \
            a_[mi_], b_[ni_], acc[(MH) * 4 + mi_][ni_], 0, 0, 0);              \
    __builtin_amdgcn_s_setprio(0);                                             \
    VMCNT(4);                                                                  \
    SBAR();                                                                    \
  }

  // prologue: tile 0 (all regions) + A-kh0 of tile 1
  STG(0, 0) STG(0, 1) STG(0, 2) STG(0, 3) STG(1, 0)
  VMCNT(0);
  SBAR();

  for (int I = 0; I < (nt >> 1); ++I) {
    const int u = 2 * I;
    PH(0, 0, u,     u + 1, 1)   // p1: reads A0,B0(u);  stage B-kh0(u+1)
    PH(0, 1, u,     u + 1, 2)   // p2: reads A1,B1(u);  stage A-kh1(u+1)
    PH(1, 0, u,     u + 1, 3)   // p3: reads A0,B0(u);  stage B-kh1(u+1)
    PH(1, 1, u,     u + 2, 0)   // p4: reads A1,B1(u);  stage A-kh0(u+2)
    PH(0, 0, u + 1, u + 2, 1)   // p5
    PH(0, 1, u + 1, u + 2, 2)   // p6
    PH(1, 0, u + 1, u + 2, 3)   // p7
    PH(1, 1, u + 1, u + 3, 0)   // p8
  }

  VMCNT(0);
  LGKM(0);
  __syncthreads();

  // ---- vectorized epilogue: per-wave LDS transpose to row-major 16-col chunks
  constexpr int EPS = 68;
  const int fr = lane & 15;
  const int fq = (lane >> 4) * 4;
  const int er = lane >> 2;
  const int ec = (lane & 3) * 16;
  const long gc0 = colBase + wn * 64 + ec;
  float* ep = (float*)smem + wid * (16 * EPS);

  f32x4 biasv[4], maskv[4], av[4];
  float sc = 0.f;
  auto load_add = [&](long gr) {
    if constexpr (EPI == 1) {
      const float* am = (const float*)addmat;
#pragma unroll
      for (int i = 0; i < 4; ++i) av[i] = *(const f32x4*)&am[gr * N + gc0 + i * 4];
    } else if constexpr (EPI == 5) {
      const _Float16* am = (const _Float16*)addmat;
      f16x8 h0 = *(const f16x8*)&am[gr * N + gc0];
      f16x8 h1 = *(const f16x8*)&am[gr * N + gc0 + 8];
#pragma unroll
      for (int i = 0; i < 4; ++i) {
        const f16x8& hh = i < 2 ? h0 : h1;
        const int o = (i & 1) * 4;
        av[i][0] = (float)hh[o]; av[i][1] = (float)hh[o + 1];
        av[i][2] = (float)hh[o + 2]; av[i][3] = (float)hh[o + 3];
      }
    }
  };
  if constexpr (EPI == 1 || EPI == 5) {
#pragma unroll
    for (int i = 0; i < 4; ++i) biasv[i] = *(const f32x4*)&bias[gc0 + i * 4];
    load_add(rowBase + wm * 128 + er);
  }
  if constexpr (EPI == 2) {
#pragma unroll
    for (int i = 0; i < 4; ++i)
      maskv[i] = *(const f32x4*)&((const float*)addmat)[(size_t)z * N + gc0 + i * 4];
  }
  if constexpr (EPI == 3) sc = extra[z];

#pragma unroll
  for (int mf = 0; mf < 8; ++mf) {
#pragma unroll
    for (int n = 0; n < 4; ++n)
#pragma unroll
      for (int j = 0; j < 4; ++j)
        ep[(fq + j) * EPS + n * 16 + fr] = acc[mf][n][j];
    __syncthreads();
    const long gr = rowBase + wm * 128 + mf * 16 + er;
    f32x4 r[4];
#pragma unroll
    for (int i = 0; i < 4; ++i) r[i] = *(const f32x4*)&ep[er * EPS + ec + i * 4];
    f32x4 a_cur[4];
    if constexpr (EPI == 1 || EPI == 5) {
#pragma unroll
      for (int i = 0; i < 4; ++i) a_cur[i] = av[i];
      if (mf < 7) load_add(gr + 16);
    }
    if constexpr (EPI == 1) {
      _Float16* o = (_Float16*)outp + gr * N + gc0;
#pragma unroll
      for (int g = 0; g < 2; ++g) {
        f32x4 v0 = (r[2 * g] + biasv[2 * g] + a_cur[2 * g]) * SCALE_F;
        f32x4 v1 = (r[2 * g + 1] + biasv[2 * g + 1] + a_cur[2 * g + 1]) * SCALE_F;
        f16x8 h;
        h[0]=(_Float16)v0[0]; h[1]=(_Float16)v0[1]; h[2]=(_Float16)v0[2]; h[3]=(_Float16)v0[3];
        h[4]=(_Float16)v1[0]; h[5]=(_Float16)v1[1]; h[6]=(_Float16)v1[2]; h[7]=(_Float16)v1[3];
        *(f16x8*)(o + g * 8) = h;
      }
    } else if constexpr (EPI == 2) {
      float* o = (float*)outp + (size_t)z * oStride + gr * N + gc0;
#pragma unroll
      for (int i = 0; i < 4; ++i) *(f32x4*)(o + i * 4) = r[i] + maskv[i];
    } else if constexpr (EPI == 3) {
      _Float16* o = (_Float16*)outp + (size_t)z * oStride + gr * N + gc0;
#pragma unroll
      for (int g = 0; g < 2; ++g) {
        f32x4 v0 = r[2 * g] * sc;
        f32x4 v1 = r[2 * g + 1] * sc;
        f16x8 h;
        h[0]=(_Float16)v0[0]; h[1]=(_Float16)v0[1]; h[2]=(_Float16)v0[2]; h[3]=(_Float16)v0[3];
        h[4]=(_Float16)v1[0]; h[5]=(_Float16)v1[1]; h[6]=(_Float16)v1[2]; h[7]=(_Float16)v1[3];
        *(f16x8*)(o + g * 8) = h;
      }
    } else {
      float* o = (float*)outp + gr * N + gc0;
#pragma unroll
      for (int i = 0; i < 4; ++i)
        *(f32x4*)(o + i * 4) = (r[i] + biasv[i] + a_cur[i]) * SCALE_F;
    }
    __syncthreads();
  }
}

// -------------------------------------------------------------------- softmax
__global__ __launch_bounds__(256) void softmax_k(float* __restrict__ attn,
                                                 _Float16* __restrict__ attn16) {
  const size_t row = blockIdx.x;
  float* p = attn + row * SS;
  const int t = threadIdx.x;
  f32x4 v = *(const f32x4*)(p + t * 4);
  __shared__ float red[8];
  float m = fmaxf(fmaxf(v[0], v[1]), fmaxf(v[2], v[3]));
#pragma unroll
  for (int o = 32; o; o >>= 1) m = fmaxf(m, __shfl_xor(m, o));
  if (!(t & 63)) red[t >> 6] = m;
  __syncthreads();
  m = fmaxf(fmaxf(red[0], red[1]), fmaxf(red[2], red[3]));
  f32x4 e;
  e[0] = __expf(v[0] - m); e[1] = __expf(v[1] - m);
  e[2] = __expf(v[2] - m); e[3] = __expf(v[3] - m);
  float s = e[0] + e[1] + e[2] + e[3];
#pragma unroll
  for (int o = 32; o; o >>= 1) s += __shfl_xor(s, o);
  if (!(t & 63)) red[4 + (t >> 6)] = s;
  __syncthreads();
  s = red[4] + red[5] + red[6] + red[7];
  const float inv = 1.0f / s;
  f32x4 o4; o4[0]=e[0]*inv; o4[1]=e[1]*inv; o4[2]=e[2]*inv; o4[3]=e[3]*inv;
  *(f32x4*)(p + t * 4) = o4;
  f16x4 h; h[0]=(_Float16)o4[0]; h[1]=(_Float16)o4[1];
  h[2]=(_Float16)o4[2]; h[3]=(_Float16)o4[3];
  *(f16x4*)(attn16 + row * SS + t * 4) = h;
}

// -------------------------------------------------------------------- launch
extern "C" void kernel_launch(void* const* d_in, const int* in_sizes, int n_in,
                              void* d_out, int out_size, void* d_ws, size_t ws_size,
                              hipStream_t stream) {
  const float* x     = (const float*)d_in[0];
  const float* te    = (const float*)d_in[1];
  const float* keys  = (const float*)d_in[2];
  const float* vals  = (const float*)d_in[3];
  const void*  mask  = d_in[4];
  const float* w_in  = (const float*)d_in[5];
  const float* b_in  = (const float*)d_in[6];
  const float* w_out = (const float*)d_in[7];
  const float* b_out = (const float*)d_in[8];

  char* ws = (char*)d_ws;
  const size_t MB32 = 33554432;
  _Float16* buf0   = (_Float16*)(ws);              // x16 (lives to the end)
  _Float16* buf1   = (_Float16*)(ws + MB32);       // h16 -> attn16 (in place)
  _Float16* keysT  = (_Float16*)(ws + 2 * MB32);   // keysT -> ctx16 after sm
  _Float16* valsT  = (_Float16*)(ws + 3 * MB32);
  _Float16* win16  = (_Float16*)(ws + 4 * MB32);
  _Float16* wout16 = (_Float16*)(ws + 4 * MB32 + 2097152);
  float*    maskneg= (float*)   (ws + 4 * MB32 + 2 * 2097152);
  float*    sscale = (float*)   (ws + 4 * MB32 + 2 * 2097152 + 65536);

  float* out_main = (float*)d_out;
  float* attn_out = (float*)d_out + (size_t)BB * TT * CC;

  cvt_f16<<<dim3(16777216 / 2048), 256, 0, stream>>>(x, buf0, 16777216);
  cvt_f16<<<dim3(1048576 / 2048), 256, 0, stream>>>(w_in, win16, 1048576);
  cvt_f16<<<dim3(1048576 / 2048), 256, 0, stream>>>(w_out, wout16, 1048576);
  transpose_cvt<<<dim3(SS / 64, EE / 64, BB), 256, 0, stream>>>(keys, keysT, EE, SS);
  transpose_cvt<<<dim3(EE / 64, SS / 64, BB), 256, 0, stream>>>(vals, valsT, SS, EE);
  mask_prep<<<dim3(BB), 256, 0, stream>>>((const unsigned char*)mask, maskneg, sscale);

  // GEMM1: h16 = (x16 @ w_in^T + b_in + te)*s
  gemm8p<1><<<dim3(EE / 256, (BB * TT) / 256, 1), 512, 0, stream>>>(
      buf0, win16, 0, 0, 0, BB * TT, EE, CC, buf1, b_in, te, nullptr);
  // GEMM2: scores = h16 @ keysT^T + maskneg -> attn region (f32)
  gemm8p<2><<<dim3(SS / 256, TT / 256, BB), 512, 0, stream>>>(
      buf1, keysT, (long)TT * EE, (long)SS * EE, (long)TT * SS,
      TT, SS, EE, attn_out, nullptr, maskneg, nullptr);
  // softmax in-place + f16 copy into buf1
  softmax_k<<<dim3(BB * TT), 256, 0, stream>>>(attn_out, buf1);
  // GEMM3: ctx16 = (attn16 @ valsT^T)*sqrt(s_b) -> keysT region
  gemm8p<3><<<dim3(EE / 256, TT / 256, BB), 512, 0, stream>>>(
      buf1, valsT, (long)TT * SS, (long)EE * SS, (long)TT * EE,
      TT, EE, SS, keysT, nullptr, nullptr, sscale);
  // GEMM4: out = (ctx16 @ w_out^T + b_out + x16)*s  (f16 residual)
  gemm8p<5><<<dim3(CC / 256, (BB * TT) / 256, 1), 512, 0, stream>>>(
      keysT, wout16, 0, 0, 0, BB * TT, CC, EE, out_main, b_out, buf0, nullptr);
}